// Round 11
// baseline (422.451 us; speedup 1.0000x reference)
//
#include <hip/hip_runtime.h>

// SIR RK4 trajectory: 500000 rows × 3 states × 50 timesteps, f32.
// Reference quirks replicated exactly:
//   - _sir_eq returns the NEW STATE (x + f(x)), not the derivative.
//   - new = x_ORIGINAL + STEP/6*(k1+2k2+2k3+k4)  (closure over x, not prev).
// Output layout: out[row*150 + t*3 + c].
//
// Round 11: r7 structure (single-wave blocks, LDS float2-island sweep) with
// occupancy raised to 5.25 waves/SIMD.
//   Evidence: normalized kernel ~ r5:143 r6:144 r7:123 r10:155.
//   r10 (no LDS, per-lane stores) regressed: 64 lines touched per wave store
//   instr = 8x transactions -> LDS wave-linear sweep is mandatory.
//   r7 (2 waves/SIMD) beat r6 (1 wave/SIMD); remaining gap to the ~60 us
//   write floor is incomplete overlap of compute (~23 us issue-bound),
//   sweep stalls, and write drain. Fix: TCH=10 uniform chunks, 64 rows x
//   30 floats = 7.5 KiB LDS -> 21 blocks/CU = 5.25 waves/SIMD; constant
//   LDS stride (no chunk-1 16-way conflict); dense float2 sweep, 15 iters,
//   no guard in the full-block case (960 = 15*64 exactly).

#define BATCH 500000
#define NT    50
#define NF    (NT * 3)     // 150 floats per row
#define TCH   10           // timesteps per chunk; 5 uniform chunks
#define NCH   (NT / TCH)   // 5
#define CF    (TCH * 3)    // 30 floats per row per chunk
#define ROWS  64           // rows per block == threads per block (1 wave)

struct F3 { float s, i, r; };

__device__ __forceinline__ F3 sir_eq(F3 v, float b, float g, float rn) {
    float inf = b * v.s * v.i * rn;
    float rec = g * v.i;
    F3 o;
    o.s = v.s - inf;
    o.i = v.i + inf - rec;
    o.r = v.r + rec;
    return o;
}

__device__ __forceinline__ F3 rk_step(F3 prev, F3 x0, float b, float g) {
    // _sir_eq preserves the component sum, so the four divisor sums are
    // n * {1, 1.05, 1.0525, 1.10525} -> 1 rcp + 3 muls (measured absmax
    // 0.0078 vs threshold 0.0259).
    float n  = prev.s + prev.i + prev.r;
    float r1 = __builtin_amdgcn_rcpf(n);
    float r2 = r1 * 0.952380952f;  // 1/1.05
    float r3 = r1 * 0.950118765f;  // 1/1.0525
    float r4 = r1 * 0.904772676f;  // 1/1.10525

    F3 k1 = sir_eq(prev, b, g, r1);
    F3 a2 = { fmaf(0.05f, k1.s, prev.s), fmaf(0.05f, k1.i, prev.i), fmaf(0.05f, k1.r, prev.r) };
    F3 k2 = sir_eq(a2, b, g, r2);
    F3 a3 = { fmaf(0.05f, k2.s, prev.s), fmaf(0.05f, k2.i, prev.i), fmaf(0.05f, k2.r, prev.r) };
    F3 k3 = sir_eq(a3, b, g, r3);
    F3 a4 = { fmaf(0.10f, k3.s, prev.s), fmaf(0.10f, k3.i, prev.i), fmaf(0.10f, k3.r, prev.r) };
    F3 k4 = sir_eq(a4, b, g, r4);

    const float C = (float)(0.1 / 6.0);
    F3 nw;
    nw.s = fmaf(C, (k1.s + k4.s) + 2.0f * (k2.s + k3.s), x0.s);
    nw.i = fmaf(C, (k1.i + k4.i) + 2.0f * (k2.i + k3.i), x0.i);
    nw.r = fmaf(C, (k1.r + k4.r) + 2.0f * (k2.r + k3.r), x0.r);
    return nw;
}

__global__ __launch_bounds__(ROWS) void sir_rk4_kernel(
        const float* __restrict__ x,
        const float* __restrict__ beta,
        const float* __restrict__ gamma,
        float* __restrict__ out) {
    // [64 rows][30 floats], constant stride for all 5 chunks. Staging writes
    // 4-way bank-aliased (stride 30 ≡ -2 mod 32) — ~5% of instrs at 1.58x,
    // negligible. Sweep reads dense float2 (l2[li]), sweep writes contiguous
    // 120B islands per row (8B-aligned: 600r + 120c + 8g).
    __shared__ __align__(16) float lds[ROWS * CF];   // 7680 B -> 21 blocks/CU

    const int lane  = threadIdx.x;
    const int row0  = blockIdx.x * ROWS;
    const int row   = row0 + lane;
    const int nrows = min(ROWS, BATCH - row0);
    const bool active = lane < nrows;
    const bool fullblk = (nrows == ROWS);

    const float b = beta[0];
    const float g = gamma[0];

    F3 xv = { 1.0f, 1.0f, 1.0f };                    // benign for tail lanes
    if (active) {
        xv.s = x[(size_t)row * 3 + 0];
        xv.i = x[(size_t)row * 3 + 1];
        xv.r = x[(size_t)row * 3 + 2];
    }

    float* myrow = lds + lane * CF;
    F3 prev = xv;

    for (int c = 0; c < NCH; ++c) {
        // ---- compute TCH states for this chunk into LDS ----
        if (c == 0) {
            myrow[0] = xv.s; myrow[1] = xv.i; myrow[2] = xv.r;   // t=0 is x
        } else {
            prev = rk_step(prev, xv, b, g);
            myrow[0] = prev.s; myrow[1] = prev.i; myrow[2] = prev.r;
        }
        #pragma unroll
        for (int tt = 1; tt < TCH; ++tt) {
            prev = rk_step(prev, xv, b, g);
            myrow[tt * 3 + 0] = prev.s;
            myrow[tt * 3 + 1] = prev.i;
            myrow[tt * 3 + 2] = prev.r;
        }
        __syncthreads();                              // 1 wave: cheap drain

        // ---- sweep: 15 float2 per row, wave-linear in LDS ----
        const float2* l2 = (const float2*)lds;
        if (fullblk) {
            #pragma unroll
            for (int it = 0; it < CF / 2; ++it) {     // 15, li in [0,960)
                int li = it * ROWS + lane;
                int r  = li / (CF / 2);               // magic-mul div by 15
                int gg = li - r * (CF / 2);
                *reinterpret_cast<float2*>(
                    out + (size_t)(row0 + r) * NF + c * CF + 2 * gg) = l2[li];
            }
        } else {
            const int total2 = nrows * (CF / 2);
            for (int it = 0; it < CF / 2; ++it) {
                int li = it * ROWS + lane;
                if (li < total2) {
                    int r  = li / (CF / 2);
                    int gg = li - r * (CF / 2);
                    *reinterpret_cast<float2*>(
                        out + (size_t)(row0 + r) * NF + c * CF + 2 * gg) = l2[li];
                }
            }
        }
        __syncthreads();                              // sweep reads before LDS reuse
    }
}

extern "C" void kernel_launch(void* const* d_in, const int* in_sizes, int n_in,
                              void* d_out, int out_size, void* d_ws, size_t ws_size,
                              hipStream_t stream) {
    const float* x     = (const float*)d_in[0];
    const float* beta  = (const float*)d_in[1];
    const float* gamma = (const float*)d_in[2];
    float* out = (float*)d_out;

    const int grid = (BATCH + ROWS - 1) / ROWS;      // 7813
    sir_rk4_kernel<<<grid, ROWS, 0, stream>>>(x, beta, gamma, out);
}